// Round 11
// baseline (460.211 us; speedup 1.0000x reference)
//
#include <hip/hip_runtime.h>

#define SEQ 8192
#define DIM 768

typedef __attribute__((ext_vector_type(8))) short s16x8;   // 8 x bf16
typedef __attribute__((ext_vector_type(4))) float f32x4;

// RNE float -> bf16
__device__ __forceinline__ unsigned short f2bf(float f) {
  union { float f; unsigned u; } v; v.f = f;
  unsigned r = v.u + 0x7FFFu + ((v.u >> 16) & 1u);
  return (unsigned short)(r >> 16);
}

__device__ __forceinline__ float bf2f(unsigned short s) {
  union { unsigned u; float f; } v; v.u = ((unsigned)s) << 16;
  return v.f;
}

// async global->LDS 16B copy: lds dest = wave-uniform base + lane*16
__device__ __forceinline__ void gll16(const void* gsrc, void* ldst) {
  __builtin_amdgcn_global_load_lds(
      (__attribute__((address_space(1))) unsigned int*)gsrc,
      (__attribute__((address_space(3))) unsigned int*)ldst, 16, 0, 0);
}

// ---------------- fused cast kernel: x (6144 blocks) + wq/wk/wv (576 each) ----------------
#define XN4 (SEQ * DIM / 4)     // 1572864
#define WN4 (DIM * DIM / 4)     // 147456

__global__ void cast_all_kernel(const float* __restrict__ x, const float* __restrict__ wq,
                                const float* __restrict__ wk, const float* __restrict__ wv,
                                unsigned short* __restrict__ dx, unsigned short* __restrict__ dq,
                                unsigned short* __restrict__ dk, unsigned short* __restrict__ dv) {
  int i = blockIdx.x * blockDim.x + threadIdx.x;
  const float* s;
  unsigned short* d;
  int off;
  if (i < XN4) {
    s = x; d = dx; off = i;
  } else {
    int j = i - XN4;
    int wi = j / WN4;
    off = j - wi * WN4;
    s = (wi == 0) ? wq : ((wi == 1) ? wk : wv);
    d = (wi == 0) ? dq : ((wi == 1) ? dk : dv);
  }
  float4 v = ((const float4*)s)[off];
  ushort4 r; r.x = f2bf(v.x); r.y = f2bf(v.y); r.z = f2bf(v.z); r.w = f2bf(v.w);
  ((ushort4*)d)[off] = r;
}

// ---------------- projection GEMM: C[m][n] = sum_k X[m][k]*W[n][k] ----------------
// z==0 writes Q fragment-linear: Qf[row>>4][col>>3][row&15][col&7]  (16B frag rows)
// z==1 writes K normal [row][dim]; z==2 writes Vt blocked [key>>5][vr][key&31]
__global__ __launch_bounds__(256, 2)
void proj_kernel(const unsigned short* __restrict__ X,
                 const unsigned short* __restrict__ Wq,
                 const unsigned short* __restrict__ Wk,
                 const unsigned short* __restrict__ Wv,
                 unsigned short* __restrict__ Qb,
                 unsigned short* __restrict__ Kb,
                 unsigned short* __restrict__ Vtb) {
  __shared__ __align__(16) char lds[65536];
  const int tid = threadIdx.x;
  const int lane = tid & 63, wv = tid >> 6;
  const int l15 = lane & 15, l4 = lane >> 4;
  const int mt = blockIdx.x, nt = blockIdx.y, z = blockIdx.z;
  const unsigned short* W = (z == 0) ? Wq : ((z == 1) ? Wk : Wv);

  f32x4 acc[4][4];
#pragma unroll
  for (int i = 0; i < 4; ++i)
#pragma unroll
    for (int j = 0; j < 4; ++j) acc[i][j] = f32x4{0.f, 0.f, 0.f, 0.f};

  auto stage = [&](int kk) {
    char* At = lds + (kk & 1) * 32768;
    char* Bt = At + 16384;
    const int d0 = kk * 64;
#pragma unroll
    for (int i = 0; i < 4; ++i) {
      int s = i * 256 + tid;
      int row = s >> 3, c = (s & 7) ^ (row & 7);
      gll16(X + (long)(mt * 128 + row) * DIM + d0 + c * 8, At + i * 4096 + (wv << 10));
      gll16(W + (long)(nt * 128 + row) * DIM + d0 + c * 8, Bt + i * 4096 + (wv << 10));
    }
  };

  stage(0);
#pragma unroll 1
  for (int kk = 0; kk < 12; ++kk) {
    __syncthreads();
    if (kk + 1 < 12) stage(kk + 1);
    const char* At = lds + (kk & 1) * 32768;
    const char* Bt = At + 16384;
#pragma unroll
    for (int ks = 0; ks < 2; ++ks) {
      const int c = ks * 4 + l4;
      s16x8 a[4], b[4];
#pragma unroll
      for (int mi = 0; mi < 4; ++mi) {
        int row = (wv & 1) * 64 + mi * 16 + l15;
        a[mi] = *(const s16x8*)(At + row * 128 + ((c ^ (row & 7)) << 4));
      }
#pragma unroll
      for (int ni = 0; ni < 4; ++ni) {
        int row = (wv >> 1) * 64 + ni * 16 + l15;
        b[ni] = *(const s16x8*)(Bt + row * 128 + ((c ^ (row & 7)) << 4));
      }
#pragma unroll
      for (int mi = 0; mi < 4; ++mi)
#pragma unroll
        for (int ni = 0; ni < 4; ++ni)
          acc[mi][ni] = __builtin_amdgcn_mfma_f32_16x16x32_bf16(a[mi], b[ni], acc[mi][ni], 0, 0, 0);
    }
  }

#pragma unroll
  for (int mi = 0; mi < 4; ++mi)
#pragma unroll
    for (int ni = 0; ni < 4; ++ni) {
      int row0 = mt * 128 + (wv & 1) * 64 + mi * 16 + l4 * 4;
      int col = nt * 128 + (wv >> 1) * 64 + ni * 16 + l15;
      if (z == 2) {
        ushort4 r;
        r.x = f2bf(acc[mi][ni][0]); r.y = f2bf(acc[mi][ni][1]);
        r.z = f2bf(acc[mi][ni][2]); r.w = f2bf(acc[mi][ni][3]);
        // blocked: [row0>>5][col][row0&31]; keys row0..row0+3 stay in one 32-block
        *(ushort4*)(Vtb + (long)(row0 >> 5) * (DIM * 32) + col * 32 + (row0 & 31)) = r;
      } else if (z == 0) {
        // fragment-linear Qf: [(row>>4)*96 + col>>3][row&15][col&7]
        const long fb = ((long)(row0 >> 4) * 96 + (col >> 3)) * 128 + (col & 7);
#pragma unroll
        for (int g = 0; g < 4; ++g)
          Qb[fb + (l4 * 4 + g) * 8] = f2bf(acc[mi][ni][g]);
      } else {
#pragma unroll
        for (int g = 0; g < 4; ++g)
          Kb[(long)(row0 + g) * DIM + col] = f2bf(acc[mi][ni][g]);
      }
    }
}

// ---------------- flash attention: Q direct (fragment-linear), K LDS BK=128, V direct ----
// BM=64 q rows/block, BN=256 keys/iter, 8 waves, all 16x16x32 MFMA.
// QK: 6 rounds of 128 dims; K staged 64KB/round (2x64KB dbuf); Q af fragments
//   loaded 1KB-contiguous from Qf at round start (latency under 64 MFMAs).
// PV: verbatim R10 (V direct global->reg ping-pong; barrier-free).
// Barriers: 6 K-rounds + 1 P-visibility = 7/iter (was 13).
// LDS (163840): K B0=[0,65536) B1=[65536,131072); P=[131072,163840);
//   l_part aliases lds[0,1024) post-loop.
// K swizzle (256B rows): data (row,c8) at byte row*256 + ((c8^(row&15))<<4);
//   bk lane bank-start = ((ks*4+l4)^l15)*4 mod 32 -> 2 lanes/bank = free.
// Rotation: round r reads buf r&1, stages buf (r+1)&1; r=5 (reads B1) stages
//   next-iter K(0) -> B0 (B0 last read r=4; its readers passed the r=5 barrier).
// P hazard: P written next after 6 next-iter barriers -> PV readers long done.
#define SCALE_LOG2E 0.05205878f  // (1/sqrt(768)) * log2(e)

#define LOADVB(arr, vv)                                                            \
  do {                                                                             \
    const unsigned short* Vb_ = V + (long)(kblk0 + (vv)) * (DIM * 32);             \
    _Pragma("unroll")                                                              \
    for (int j_ = 0; j_ < 6; ++j_)                                                 \
      arr[j_] = *(const s16x8*)(Vb_ + (j_ * 128 + wv * 16 + l15) * 32 + l4 * 8);   \
  } while (0)

#define PVCHUNK(vv, CUR, NXT)                                                      \
  do {                                                                             \
    if ((vv) + 1 < 8) LOADVB(NXT, (vv) + 1);                                       \
    s16x8 pa_[4];                                                                  \
    const int ck_ = (vv) * 4 + l4;                                                 \
    _Pragma("unroll")                                                              \
    for (int rs_ = 0; rs_ < 4; ++rs_) {                                            \
      int row_ = rs_ * 16 + l15;                                                   \
      int pc_ = (ck_ & ~7) | ((ck_ & 7) ^ (row_ & 7));                             \
      pa_[rs_] = *(const s16x8*)(Pl + row_ * 512 + (pc_ << 4));                    \
    }                                                                              \
    __builtin_amdgcn_s_setprio(1);                                                 \
    _Pragma("unroll")                                                              \
    for (int j_ = 0; j_ < 6; ++j_)                                                 \
      _Pragma("unroll")                                                            \
      for (int rs_ = 0; rs_ < 4; ++rs_)                                            \
        acc_o[rs_][j_] =                                                           \
            __builtin_amdgcn_mfma_f32_16x16x32_bf16(pa_[rs_], CUR[j_], acc_o[rs_][j_], 0, 0, 0); \
    __builtin_amdgcn_s_setprio(0);                                                 \
  } while (0)

__global__ __launch_bounds__(512, 2)
void flash_kernel(const unsigned short* __restrict__ Qf,  // fragment-linear Q
                  const unsigned short* __restrict__ K,   // [8192][768] bf16
                  const unsigned short* __restrict__ V,   // blocked Vt [256][768][32] bf16
                  unsigned short* __restrict__ partp,     // [G][8192][768] bf16 (G-split mode)
                  float* __restrict__ outf,               // [8192][768] fp32 (norm mode)
                  float* __restrict__ lout,               // [G][8192] (G-split mode)
                  int kv_len, int norm_out) {
  __shared__ __align__(16) char lds[163840];
  char* Pl = lds + 131072;
  float* l_part = (float*)lds;  // [4][64], used only after the main loop

  const int tid = threadIdx.x;
  const int lane = tid & 63, wv = tid >> 6;
  const int l15 = lane & 15, l4 = lane >> 4;
  const int qtile = blockIdx.x, split = blockIdx.y;
  const long kv0 = (long)split * kv_len;
  const long qrow0 = (long)qtile * 64;
  const int R = wv & 1;   // S row-half
  const int C = wv >> 1;  // S key-quarter

  f32x4 acc_o[4][6];
  float acc_lp[8];
#pragma unroll
  for (int i = 0; i < 4; ++i)
#pragma unroll
    for (int j = 0; j < 6; ++j) acc_o[i][j] = f32x4{0.f, 0.f, 0.f, 0.f};
#pragma unroll
  for (int i = 0; i < 8; ++i) acc_lp[i] = 0.f;

  const int niter = kv_len >> 8;

  // K stage: round r covers dims [r*128, r*128+128). 64KB, 256B rows,
  // swizzled source (linear dest): slot s -> row=s>>4, p=s&15, c8=p^(row&15).
  auto stageK = [&](int r, long kbase) {
    char* Kc = lds + (r & 1) * 65536;
    const int d0 = r * 128;
#pragma unroll
    for (int i = 0; i < 8; ++i) {
      int s = i * 512 + tid;          // 4096 slots of 16B
      int row = s >> 4, p = s & 15;
      int c = p ^ (row & 15);
      gll16(K + (kbase + row) * DIM + d0 + c * 8, Kc + i * 8192 + (wv << 10));
    }
  };

  stageK(0, kv0);
#pragma unroll 1
  for (int it = 0; it < niter; ++it) {
    const long kb = kv0 + (long)it * 256;
    const long kblk0 = kb >> 5;

    // ---- QK: S[64x256], per-wave region [32 rows x 64 keys] = 2x4 16x16 tiles ----
    f32x4 acc_s[2][4];
#pragma unroll
    for (int a = 0; a < 2; ++a)
#pragma unroll
      for (int b = 0; b < 4; ++b) acc_s[a][b] = f32x4{0.f, 0.f, 0.f, 0.f};

    const int tile16q = qtile * 4 + R * 2;   // +rt

#pragma unroll 1
    for (int r = 0; r < 6; ++r) {
      __syncthreads();  // drains stage(r); all waves done with prior compute
      if (r + 1 < 6) stageK(r + 1, kb);
      else if (it + 1 < niter) stageK(0, kb + 256);  // dest B0; r=5 reads B1
      const char* Kc = lds + (r & 1) * 65536;
      // all 8 Q fragments of this round: 1KB-contiguous loads, issued up front
      s16x8 af[2][4];
#pragma unroll
      for (int rt = 0; rt < 2; ++rt)
#pragma unroll
        for (int ks = 0; ks < 4; ++ks)
          af[rt][ks] = *(const s16x8*)(Qf +
              (((long)(tile16q + rt) * 96 + (r * 16 + ks * 4 + l4)) * 16 + l15) * 8);
#pragma unroll
      for (int ks = 0; ks < 4; ++ks) {
        s16x8 bk[4];
#pragma unroll
        for (int ct = 0; ct < 4; ++ct) {
          int kr = C * 64 + ct * 16 + l15;
          bk[ct] = *(const s16x8*)(Kc + kr * 256 + (((ks * 4 + l4) ^ (kr & 15)) << 4));
        }
        __builtin_amdgcn_s_setprio(1);
#pragma unroll
        for (int rt = 0; rt < 2; ++rt)
#pragma unroll
          for (int ct = 0; ct < 4; ++ct)
            acc_s[rt][ct] = __builtin_amdgcn_mfma_f32_16x16x32_bf16(af[rt][ks], bk[ct], acc_s[rt][ct], 0, 0, 0);
        __builtin_amdgcn_s_setprio(0);
      }
    }

    // ---- prefetch PV chunk 0's V fragments (latency hidden under exp phase) ----
    s16x8 vbA[6], vbB[6];
    LOADVB(vbA, 0);

    // ---- P = exp(S/sqrt(D)) -> bf16 -> LDS (swizzled [64][256]); per-lane l partials ----
#pragma unroll
    for (int rt = 0; rt < 2; ++rt)
#pragma unroll
      for (int ct = 0; ct < 4; ++ct)
#pragma unroll
        for (int g = 0; g < 4; ++g) {
          float p = exp2f(acc_s[rt][ct][g] * SCALE_LOG2E);
          acc_lp[rt * 4 + g] += p;
          int row = R * 32 + rt * 16 + l4 * 4 + g;
          int col = C * 64 + ct * 16 + l15;
          int off = row * 512 + ((((col >> 3) ^ (row & 7))) << 4) + ((col & 7) << 1);
          *(unsigned short*)(Pl + off) = f2bf(p);
        }
    __syncthreads();  // P visible to all waves (also drains vbA / next-iter K loads)

    // ---- PV: O[64x768] += P[64x256] @ V; 8 chunks; vb ping-pong from global ----
    PVCHUNK(0, vbA, vbB);
    PVCHUNK(1, vbB, vbA);
    PVCHUNK(2, vbA, vbB);
    PVCHUNK(3, vbB, vbA);
    PVCHUNK(4, vbA, vbB);
    PVCHUNK(5, vbB, vbA);
    PVCHUNK(6, vbA, vbB);
    PVCHUNK(7, vbB, vbA);
  }

  // ---- l reduction: butterfly over lane bits 0..3 (16 cols/group), combine quarters ----
#pragma unroll
  for (int i = 0; i < 8; ++i) {
    float v = acc_lp[i];
    v += __shfl_xor(v, 1); v += __shfl_xor(v, 2);
    v += __shfl_xor(v, 4); v += __shfl_xor(v, 8);
    acc_lp[i] = v;
  }
  __syncthreads();  // all staging/reads done before l_part alias use
  if (l15 == 0) {
#pragma unroll
    for (int rt = 0; rt < 2; ++rt)
#pragma unroll
      for (int g = 0; g < 4; ++g)
        l_part[C * 64 + R * 32 + rt * 16 + l4 * 4 + g] = acc_lp[rt * 4 + g];
  }
  __syncthreads();

  if (!norm_out) {
    if (tid < 64)
      lout[(long)split * SEQ + qrow0 + tid] =
          l_part[tid] + l_part[64 + tid] + l_part[128 + tid] + l_part[192 + tid];
#pragma unroll
    for (int rt = 0; rt < 4; ++rt) {
      int row = rt * 16 + l4 * 4;
#pragma unroll
      for (int j = 0; j < 6; ++j) {
        int cc = j >> 1, t = j & 1;
        int col = (cc * 16 + wv + 8 * t) * 16 + l15;
#pragma unroll
        for (int g = 0; g < 4; ++g)
          partp[(long)split * SEQ * DIM + (qrow0 + row + g) * DIM + col] = f2bf(acc_o[rt][j][g]);
      }
    }
  } else {
    float linv[4][4];
#pragma unroll
    for (int rt = 0; rt < 4; ++rt)
#pragma unroll
      for (int g = 0; g < 4; ++g) {
        int row = rt * 16 + l4 * 4 + g;
        linv[rt][g] = 1.0f / (l_part[row] + l_part[64 + row] + l_part[128 + row] + l_part[192 + row]);
      }
#pragma unroll
    for (int rt = 0; rt < 4; ++rt) {
      int row = rt * 16 + l4 * 4;
#pragma unroll
      for (int j = 0; j < 6; ++j) {
        int cc = j >> 1, t = j & 1;
        int col = (cc * 16 + wv + 8 * t) * 16 + l15;
#pragma unroll
        for (int g = 0; g < 4; ++g)
          outf[(qrow0 + row + g) * DIM + col] = acc_o[rt][j][g] * linv[rt][g];
      }
    }
  }
}

// ---------------- combine (G=2): out = (p0+p1)/(l0+l1), partials bf16 ----------------
__global__ void combine_kernel(const unsigned short* __restrict__ part,
                               const float* __restrict__ lsum,
                               float* __restrict__ out, int n4) {
  int i = blockIdx.x * blockDim.x + threadIdx.x;
  if (i >= n4) return;
  int row = (i * 4) / DIM;
  ushort4 p0 = ((const ushort4*)part)[i];
  ushort4 p1 = ((const ushort4*)(part + (long)SEQ * DIM))[i];
  float inv = 1.0f / (lsum[row] + lsum[SEQ + row]);
  float4 o;
  o.x = (bf2f(p0.x) + bf2f(p1.x)) * inv;
  o.y = (bf2f(p0.y) + bf2f(p1.y)) * inv;
  o.z = (bf2f(p0.z) + bf2f(p1.z)) * inv;
  o.w = (bf2f(p0.w) + bf2f(p1.w)) * inv;
  ((float4*)out)[i] = o;
}

// ---------------- host (G=2 max — the verified fast config) ----------------
extern "C" void kernel_launch(void* const* d_in, const int* in_sizes, int n_in,
                              void* d_out, int out_size, void* d_ws, size_t ws_size,
                              hipStream_t stream) {
  const float* x = (const float*)d_in[0];
  const float* wq = (const float*)d_in[1];
  const float* wk = (const float*)d_in[2];
  const float* wv = (const float*)d_in[3];
  float* out = (float*)d_out;
  char* ws = (char*)d_ws;

  const size_t o_xbf = 0;
  const size_t o_wq = o_xbf + (size_t)SEQ * DIM * 2;
  const size_t o_wk = o_wq + (size_t)DIM * DIM * 2;
  const size_t o_wv = o_wk + (size_t)DIM * DIM * 2;
  const size_t o_q = o_wv + (size_t)DIM * DIM * 2;
  const size_t o_k = o_q + (size_t)SEQ * DIM * 2;
  const size_t o_vt = o_k + (size_t)SEQ * DIM * 2;
  const size_t o_part = o_vt + (size_t)SEQ * DIM * 2;
  const size_t o_l = o_part + (size_t)2 * SEQ * DIM * 2;   // bf16 partials
  const size_t total_g2 = o_l + (size_t)2 * SEQ * 4;

  unsigned short* Xbf = (unsigned short*)(ws + o_xbf);
  unsigned short* Wqb = (unsigned short*)(ws + o_wq);
  unsigned short* Wkb = (unsigned short*)(ws + o_wk);
  unsigned short* Wvb = (unsigned short*)(ws + o_wv);
  unsigned short* Qb = (unsigned short*)(ws + o_q);   // fragment-linear Qf
  unsigned short* Kb = (unsigned short*)(ws + o_k);
  unsigned short* Vtb = (unsigned short*)(ws + o_vt);
  unsigned short* part = (unsigned short*)(ws + o_part);
  float* lbuf = (float*)(ws + o_l);

  const int G = (ws_size >= total_g2) ? 2 : 1;

  cast_all_kernel<<<7872, 256, 0, stream>>>(x, wq, wk, wv, Xbf, Wqb, Wkb, Wvb);
  proj_kernel<<<dim3(64, 6, 3), 256, 0, stream>>>(Xbf, Wqb, Wkb, Wvb, Qb, Kb, Vtb);
  if (G == 2) {
    flash_kernel<<<dim3(128, 2), 512, 0, stream>>>(Qb, Kb, Vtb, part, nullptr, lbuf, SEQ / 2, 0);
    combine_kernel<<<6144, 256, 0, stream>>>(part, lbuf, out, SEQ * DIM / 4);
  } else {
    flash_kernel<<<dim3(128, 1), 512, 0, stream>>>(Qb, Kb, Vtb, nullptr, out, nullptr, SEQ, 1);
  }
}

// Round 12
// 364.268 us; speedup vs baseline: 1.2634x; 1.2634x over previous
//
#include <hip/hip_runtime.h>

#define SEQ 8192
#define DIM 768

typedef __attribute__((ext_vector_type(8))) short s16x8;   // 8 x bf16
typedef __attribute__((ext_vector_type(4))) float f32x4;

// RNE float -> bf16
__device__ __forceinline__ unsigned short f2bf(float f) {
  union { float f; unsigned u; } v; v.f = f;
  unsigned r = v.u + 0x7FFFu + ((v.u >> 16) & 1u);
  return (unsigned short)(r >> 16);
}

__device__ __forceinline__ float bf2f(unsigned short s) {
  union { unsigned u; float f; } v; v.u = ((unsigned)s) << 16;
  return v.f;
}

// async global->LDS 16B copy: lds dest = wave-uniform base + lane*16
__device__ __forceinline__ void gll16(const void* gsrc, void* ldst) {
  __builtin_amdgcn_global_load_lds(
      (__attribute__((address_space(1))) unsigned int*)gsrc,
      (__attribute__((address_space(3))) unsigned int*)ldst, 16, 0, 0);
}

// ---------------- fused cast kernel: x (6144 blocks) + wq/wk/wv (576 each) ----------------
#define XN4 (SEQ * DIM / 4)     // 1572864
#define WN4 (DIM * DIM / 4)     // 147456

__global__ void cast_all_kernel(const float* __restrict__ x, const float* __restrict__ wq,
                                const float* __restrict__ wk, const float* __restrict__ wv,
                                unsigned short* __restrict__ dx, unsigned short* __restrict__ dq,
                                unsigned short* __restrict__ dk, unsigned short* __restrict__ dv) {
  int i = blockIdx.x * blockDim.x + threadIdx.x;
  const float* s;
  unsigned short* d;
  int off;
  if (i < XN4) {
    s = x; d = dx; off = i;
  } else {
    int j = i - XN4;
    int wi = j / WN4;
    off = j - wi * WN4;
    s = (wi == 0) ? wq : ((wi == 1) ? wk : wv);
    d = (wi == 0) ? dq : ((wi == 1) ? dk : dv);
  }
  float4 v = ((const float4*)s)[off];
  ushort4 r; r.x = f2bf(v.x); r.y = f2bf(v.y); r.z = f2bf(v.z); r.w = f2bf(v.w);
  ((ushort4*)d)[off] = r;
}

// ---------------- projection GEMM: C[m][n] = sum_k X[m][k]*W[n][k] ----------------
// z==0 writes Q fragment-linear: Qf[row>>4][col>>3][row&15][col&7]  (16B frag rows)
// z==1 writes K normal [row][dim]; z==2 writes Vt blocked [key>>5][vr][key&31]
__global__ __launch_bounds__(256, 2)
void proj_kernel(const unsigned short* __restrict__ X,
                 const unsigned short* __restrict__ Wq,
                 const unsigned short* __restrict__ Wk,
                 const unsigned short* __restrict__ Wv,
                 unsigned short* __restrict__ Qb,
                 unsigned short* __restrict__ Kb,
                 unsigned short* __restrict__ Vtb) {
  __shared__ __align__(16) char lds[65536];
  const int tid = threadIdx.x;
  const int lane = tid & 63, wv = tid >> 6;
  const int l15 = lane & 15, l4 = lane >> 4;
  const int mt = blockIdx.x, nt = blockIdx.y, z = blockIdx.z;
  const unsigned short* W = (z == 0) ? Wq : ((z == 1) ? Wk : Wv);

  f32x4 acc[4][4];
#pragma unroll
  for (int i = 0; i < 4; ++i)
#pragma unroll
    for (int j = 0; j < 4; ++j) acc[i][j] = f32x4{0.f, 0.f, 0.f, 0.f};

  auto stage = [&](int kk) {
    char* At = lds + (kk & 1) * 32768;
    char* Bt = At + 16384;
    const int d0 = kk * 64;
#pragma unroll
    for (int i = 0; i < 4; ++i) {
      int s = i * 256 + tid;
      int row = s >> 3, c = (s & 7) ^ (row & 7);
      gll16(X + (long)(mt * 128 + row) * DIM + d0 + c * 8, At + i * 4096 + (wv << 10));
      gll16(W + (long)(nt * 128 + row) * DIM + d0 + c * 8, Bt + i * 4096 + (wv << 10));
    }
  };

  stage(0);
#pragma unroll 1
  for (int kk = 0; kk < 12; ++kk) {
    __syncthreads();
    if (kk + 1 < 12) stage(kk + 1);
    const char* At = lds + (kk & 1) * 32768;
    const char* Bt = At + 16384;
#pragma unroll
    for (int ks = 0; ks < 2; ++ks) {
      const int c = ks * 4 + l4;
      s16x8 a[4], b[4];
#pragma unroll
      for (int mi = 0; mi < 4; ++mi) {
        int row = (wv & 1) * 64 + mi * 16 + l15;
        a[mi] = *(const s16x8*)(At + row * 128 + ((c ^ (row & 7)) << 4));
      }
#pragma unroll
      for (int ni = 0; ni < 4; ++ni) {
        int row = (wv >> 1) * 64 + ni * 16 + l15;
        b[ni] = *(const s16x8*)(Bt + row * 128 + ((c ^ (row & 7)) << 4));
      }
#pragma unroll
      for (int mi = 0; mi < 4; ++mi)
#pragma unroll
        for (int ni = 0; ni < 4; ++ni)
          acc[mi][ni] = __builtin_amdgcn_mfma_f32_16x16x32_bf16(a[mi], b[ni], acc[mi][ni], 0, 0, 0);
    }
  }

#pragma unroll
  for (int mi = 0; mi < 4; ++mi)
#pragma unroll
    for (int ni = 0; ni < 4; ++ni) {
      int row0 = mt * 128 + (wv & 1) * 64 + mi * 16 + l4 * 4;
      int col = nt * 128 + (wv >> 1) * 64 + ni * 16 + l15;
      if (z == 2) {
        ushort4 r;
        r.x = f2bf(acc[mi][ni][0]); r.y = f2bf(acc[mi][ni][1]);
        r.z = f2bf(acc[mi][ni][2]); r.w = f2bf(acc[mi][ni][3]);
        // blocked: [row0>>5][col][row0&31]; keys row0..row0+3 stay in one 32-block
        *(ushort4*)(Vtb + (long)(row0 >> 5) * (DIM * 32) + col * 32 + (row0 & 31)) = r;
      } else if (z == 0) {
        // fragment-linear Qf: [(row>>4)*96 + col>>3][row&15][col&7]
        const long fb = ((long)(row0 >> 4) * 96 + (col >> 3)) * 128 + (col & 7);
#pragma unroll
        for (int g = 0; g < 4; ++g)
          Qb[fb + (l4 * 4 + g) * 8] = f2bf(acc[mi][ni][g]);
      } else {
#pragma unroll
        for (int g = 0; g < 4; ++g)
          Kb[(long)(row0 + g) * DIM + col] = f2bf(acc[mi][ni][g]);
      }
    }
}

// ---------------- flash attention: R10 structure + Q-direct (SINGLE delta) ----------------
// BM=64 q rows/block, BN=256 keys/iter, 8 waves, all 16x16x32 MFMA.
// vs R10 (301us verified): Q leaves LDS — af fragments load 1KB-contiguous from
// fragment-linear Qf (L1/L2-served; C-quad waves share -> L1 broadcast).
// K staging, 13 barriers/iter, rotation, PV (V direct global->reg ping-pong),
// P path, epilogue: byte-identical to R10. Barrier density preserved (R11 lesson).
// LDS (98304): K B0=[0,32768) B1=[32768,65536); P=[65536,98304);
//   l_part aliases lds[0,1024) post-loop.
// Rotation: round r reads buf r&1, stages buf (r+1)&1; r=11 (reads B1) stages
//   next-iter K(0) -> B0 (B0 last read r=10; readers passed the r=11 barrier).
// P hazard: P read in PV (barrier-free); next P write after 12 next-iter barriers.
#define SCALE_LOG2E 0.05205878f  // (1/sqrt(768)) * log2(e)

#define LOADVB(arr, vv)                                                            \
  do {                                                                             \
    const unsigned short* Vb_ = V + (long)(kblk0 + (vv)) * (DIM * 32);             \
    _Pragma("unroll")                                                              \
    for (int j_ = 0; j_ < 6; ++j_)                                                 \
      arr[j_] = *(const s16x8*)(Vb_ + (j_ * 128 + wv * 16 + l15) * 32 + l4 * 8);   \
  } while (0)

#define PVCHUNK(vv, CUR, NXT)                                                      \
  do {                                                                             \
    if ((vv) + 1 < 8) LOADVB(NXT, (vv) + 1);                                       \
    s16x8 pa_[4];                                                                  \
    const int ck_ = (vv) * 4 + l4;                                                 \
    _Pragma("unroll")                                                              \
    for (int rs_ = 0; rs_ < 4; ++rs_) {                                            \
      int row_ = rs_ * 16 + l15;                                                   \
      int pc_ = (ck_ & ~7) | ((ck_ & 7) ^ (row_ & 7));                             \
      pa_[rs_] = *(const s16x8*)(Pl + row_ * 512 + (pc_ << 4));                    \
    }                                                                              \
    __builtin_amdgcn_s_setprio(1);                                                 \
    _Pragma("unroll")                                                              \
    for (int j_ = 0; j_ < 6; ++j_)                                                 \
      _Pragma("unroll")                                                            \
      for (int rs_ = 0; rs_ < 4; ++rs_)                                            \
        acc_o[rs_][j_] =                                                           \
            __builtin_amdgcn_mfma_f32_16x16x32_bf16(pa_[rs_], CUR[j_], acc_o[rs_][j_], 0, 0, 0); \
    __builtin_amdgcn_s_setprio(0);                                                 \
  } while (0)

__global__ __launch_bounds__(512, 2)
void flash_kernel(const unsigned short* __restrict__ Qf,  // fragment-linear Q
                  const unsigned short* __restrict__ K,   // [8192][768] bf16
                  const unsigned short* __restrict__ V,   // blocked Vt [256][768][32] bf16
                  unsigned short* __restrict__ partp,     // [G][8192][768] bf16 (G-split mode)
                  float* __restrict__ outf,               // [8192][768] fp32 (norm mode)
                  float* __restrict__ lout,               // [G][8192] (G-split mode)
                  int kv_len, int norm_out) {
  __shared__ __align__(16) char lds[98304];
  char* Pl = lds + 65536;
  float* l_part = (float*)lds;  // [4][64], used only after the main loop

  const int tid = threadIdx.x;
  const int lane = tid & 63, wv = tid >> 6;
  const int l15 = lane & 15, l4 = lane >> 4;
  const int qtile = blockIdx.x, split = blockIdx.y;
  const long kv0 = (long)split * kv_len;
  const long qrow0 = (long)qtile * 64;
  const int R = wv & 1;   // S row-half
  const int C = wv >> 1;  // S key-quarter

  f32x4 acc_o[4][6];
  float acc_lp[8];
#pragma unroll
  for (int i = 0; i < 4; ++i)
#pragma unroll
    for (int j = 0; j < 6; ++j) acc_o[i][j] = f32x4{0.f, 0.f, 0.f, 0.f};
#pragma unroll
  for (int i = 0; i < 8; ++i) acc_lp[i] = 0.f;

  const int niter = kv_len >> 8;

  // K stage: round r covers dims [r*64, r*64+64). 32KB, 128B rows, XOR-(row&7).
  auto stageK = [&](int r, long kbase) {
    char* Kc = lds + (r & 1) * 32768;
    const int d0 = r * 64;
#pragma unroll
    for (int i = 0; i < 4; ++i) {
      int s = i * 512 + tid;
      int row = s >> 3, c = (s & 7) ^ (row & 7);
      gll16(K + (kbase + row) * DIM + d0 + c * 8, Kc + i * 8192 + (wv << 10));
    }
  };

  stageK(0, kv0);
#pragma unroll 1
  for (int it = 0; it < niter; ++it) {
    const long kb = kv0 + (long)it * 256;
    const long kblk0 = kb >> 5;

    // ---- QK: S[64x256], per-wave region [32 rows x 64 keys] = 2x4 16x16 tiles ----
    f32x4 acc_s[2][4];
#pragma unroll
    for (int a = 0; a < 2; ++a)
#pragma unroll
      for (int b = 0; b < 4; ++b) acc_s[a][b] = f32x4{0.f, 0.f, 0.f, 0.f};

    const int tile16q = qtile * 4 + R * 2;   // +rt

#pragma unroll 1
    for (int r = 0; r < 12; ++r) {
      __syncthreads();  // drains stage(r); all waves done with prior compute
      if (r + 1 < 12) stageK(r + 1, kb);
      else if (it + 1 < niter) stageK(0, kb + 256);  // dest B0; r=11 reads B1
      const char* Kc = lds + (r & 1) * 32768;
      // this round's 4 Q fragments: 1KB-contiguous global loads (Qf), issued up front
      s16x8 af[2][2];
#pragma unroll
      for (int rt = 0; rt < 2; ++rt)
#pragma unroll
        for (int ks = 0; ks < 2; ++ks)
          af[rt][ks] = *(const s16x8*)(Qf +
              ((long)(tile16q + rt) * 96 + (r * 8 + ks * 4 + l4)) * 128 + l15 * 8);
#pragma unroll
      for (int ks = 0; ks < 2; ++ks) {
        const int c = ks * 4 + l4;
        s16x8 bk[4];
#pragma unroll
        for (int ct = 0; ct < 4; ++ct) {
          int kr = C * 64 + ct * 16 + l15;
          bk[ct] = *(const s16x8*)(Kc + kr * 128 + ((c ^ (kr & 7)) << 4));
        }
        __builtin_amdgcn_s_setprio(1);
#pragma unroll
        for (int rt = 0; rt < 2; ++rt)
#pragma unroll
          for (int ct = 0; ct < 4; ++ct)
            acc_s[rt][ct] = __builtin_amdgcn_mfma_f32_16x16x32_bf16(af[rt][ks], bk[ct], acc_s[rt][ct], 0, 0, 0);
        __builtin_amdgcn_s_setprio(0);
      }
    }

    // ---- prefetch PV chunk 0's V fragments (latency hidden under exp phase) ----
    s16x8 vbA[6], vbB[6];
    LOADVB(vbA, 0);

    // ---- P = exp(S/sqrt(D)) -> bf16 -> LDS (swizzled [64][256]); per-lane l partials ----
#pragma unroll
    for (int rt = 0; rt < 2; ++rt)
#pragma unroll
      for (int ct = 0; ct < 4; ++ct)
#pragma unroll
        for (int g = 0; g < 4; ++g) {
          float p = exp2f(acc_s[rt][ct][g] * SCALE_LOG2E);
          acc_lp[rt * 4 + g] += p;
          int row = R * 32 + rt * 16 + l4 * 4 + g;
          int col = C * 64 + ct * 16 + l15;
          int off = row * 512 + ((((col >> 3) ^ (row & 7))) << 4) + ((col & 7) << 1);
          *(unsigned short*)(Pl + off) = f2bf(p);
        }
    __syncthreads();  // P visible to all waves (also drains vbA / next-iter K loads)

    // ---- PV: O[64x768] += P[64x256] @ V; 8 chunks; vb ping-pong from global ----
    PVCHUNK(0, vbA, vbB);
    PVCHUNK(1, vbB, vbA);
    PVCHUNK(2, vbA, vbB);
    PVCHUNK(3, vbB, vbA);
    PVCHUNK(4, vbA, vbB);
    PVCHUNK(5, vbB, vbA);
    PVCHUNK(6, vbA, vbB);
    PVCHUNK(7, vbB, vbA);
  }

  // ---- l reduction: butterfly over lane bits 0..3 (16 cols/group), combine quarters ----
#pragma unroll
  for (int i = 0; i < 8; ++i) {
    float v = acc_lp[i];
    v += __shfl_xor(v, 1); v += __shfl_xor(v, 2);
    v += __shfl_xor(v, 4); v += __shfl_xor(v, 8);
    acc_lp[i] = v;
  }
  __syncthreads();  // all staging/reads done before l_part alias use
  if (l15 == 0) {
#pragma unroll
    for (int rt = 0; rt < 2; ++rt)
#pragma unroll
      for (int g = 0; g < 4; ++g)
        l_part[C * 64 + R * 32 + rt * 16 + l4 * 4 + g] = acc_lp[rt * 4 + g];
  }
  __syncthreads();

  if (!norm_out) {
    if (tid < 64)
      lout[(long)split * SEQ + qrow0 + tid] =
          l_part[tid] + l_part[64 + tid] + l_part[128 + tid] + l_part[192 + tid];
#pragma unroll
    for (int rt = 0; rt < 4; ++rt) {
      int row = rt * 16 + l4 * 4;
#pragma unroll
      for (int j = 0; j < 6; ++j) {
        int cc = j >> 1, t = j & 1;
        int col = (cc * 16 + wv + 8 * t) * 16 + l15;
#pragma unroll
        for (int g = 0; g < 4; ++g)
          partp[(long)split * SEQ * DIM + (qrow0 + row + g) * DIM + col] = f2bf(acc_o[rt][j][g]);
      }
    }
  } else {
    float linv[4][4];
#pragma unroll
    for (int rt = 0; rt < 4; ++rt)
#pragma unroll
      for (int g = 0; g < 4; ++g) {
        int row = rt * 16 + l4 * 4 + g;
        linv[rt][g] = 1.0f / (l_part[row] + l_part[64 + row] + l_part[128 + row] + l_part[192 + row]);
      }
#pragma unroll
    for (int rt = 0; rt < 4; ++rt) {
      int row = rt * 16 + l4 * 4;
#pragma unroll
      for (int j = 0; j < 6; ++j) {
        int cc = j >> 1, t = j & 1;
        int col = (cc * 16 + wv + 8 * t) * 16 + l15;
#pragma unroll
        for (int g = 0; g < 4; ++g)
          outf[(qrow0 + row + g) * DIM + col] = acc_o[rt][j][g] * linv[rt][g];
      }
    }
  }
}

// ---------------- combine (G=2): out = (p0+p1)/(l0+l1), partials bf16 ----------------
__global__ void combine_kernel(const unsigned short* __restrict__ part,
                               const float* __restrict__ lsum,
                               float* __restrict__ out, int n4) {
  int i = blockIdx.x * blockDim.x + threadIdx.x;
  if (i >= n4) return;
  int row = (i * 4) / DIM;
  ushort4 p0 = ((const ushort4*)part)[i];
  ushort4 p1 = ((const ushort4*)(part + (long)SEQ * DIM))[i];
  float inv = 1.0f / (lsum[row] + lsum[SEQ + row]);
  float4 o;
  o.x = (bf2f(p0.x) + bf2f(p1.x)) * inv;
  o.y = (bf2f(p0.y) + bf2f(p1.y)) * inv;
  o.z = (bf2f(p0.z) + bf2f(p1.z)) * inv;
  o.w = (bf2f(p0.w) + bf2f(p1.w)) * inv;
  ((float4*)out)[i] = o;
}

// ---------------- host (G=2 max — the verified fast config) ----------------
extern "C" void kernel_launch(void* const* d_in, const int* in_sizes, int n_in,
                              void* d_out, int out_size, void* d_ws, size_t ws_size,
                              hipStream_t stream) {
  const float* x = (const float*)d_in[0];
  const float* wq = (const float*)d_in[1];
  const float* wk = (const float*)d_in[2];
  const float* wv = (const float*)d_in[3];
  float* out = (float*)d_out;
  char* ws = (char*)d_ws;

  const size_t o_xbf = 0;
  const size_t o_wq = o_xbf + (size_t)SEQ * DIM * 2;
  const size_t o_wk = o_wq + (size_t)DIM * DIM * 2;
  const size_t o_wv = o_wk + (size_t)DIM * DIM * 2;
  const size_t o_q = o_wv + (size_t)DIM * DIM * 2;
  const size_t o_k = o_q + (size_t)SEQ * DIM * 2;
  const size_t o_vt = o_k + (size_t)SEQ * DIM * 2;
  const size_t o_part = o_vt + (size_t)SEQ * DIM * 2;
  const size_t o_l = o_part + (size_t)2 * SEQ * DIM * 2;   // bf16 partials
  const size_t total_g2 = o_l + (size_t)2 * SEQ * 4;

  unsigned short* Xbf = (unsigned short*)(ws + o_xbf);
  unsigned short* Wqb = (unsigned short*)(ws + o_wq);
  unsigned short* Wkb = (unsigned short*)(ws + o_wk);
  unsigned short* Wvb = (unsigned short*)(ws + o_wv);
  unsigned short* Qb = (unsigned short*)(ws + o_q);   // fragment-linear Qf
  unsigned short* Kb = (unsigned short*)(ws + o_k);
  unsigned short* Vtb = (unsigned short*)(ws + o_vt);
  unsigned short* part = (unsigned short*)(ws + o_part);
  float* lbuf = (float*)(ws + o_l);

  const int G = (ws_size >= total_g2) ? 2 : 1;

  cast_all_kernel<<<7872, 256, 0, stream>>>(x, wq, wk, wv, Xbf, Wqb, Wkb, Wvb);
  proj_kernel<<<dim3(64, 6, 3), 256, 0, stream>>>(Xbf, Wqb, Wkb, Wvb, Qb, Kb, Vtb);
  if (G == 2) {
    flash_kernel<<<dim3(128, 2), 512, 0, stream>>>(Qb, Kb, Vtb, part, nullptr, lbuf, SEQ / 2, 0);
    combine_kernel<<<6144, 256, 0, stream>>>(part, lbuf, out, SEQ * DIM / 4);
  } else {
    flash_kernel<<<dim3(128, 1), 512, 0, stream>>>(Qb, Kb, Vtb, nullptr, out, nullptr, SEQ, 1);
  }
}

// Round 13
// 350.814 us; speedup vs baseline: 1.3118x; 1.0384x over previous
//
#include <hip/hip_runtime.h>

#define SEQ 8192
#define DIM 768

typedef __attribute__((ext_vector_type(8))) short s16x8;   // 8 x bf16
typedef __attribute__((ext_vector_type(4))) float f32x4;

// RNE float -> bf16
__device__ __forceinline__ unsigned short f2bf(float f) {
  union { float f; unsigned u; } v; v.f = f;
  unsigned r = v.u + 0x7FFFu + ((v.u >> 16) & 1u);
  return (unsigned short)(r >> 16);
}

__device__ __forceinline__ float bf2f(unsigned short s) {
  union { unsigned u; float f; } v; v.u = ((unsigned)s) << 16;
  return v.f;
}

// async global->LDS 16B copy: lds dest = wave-uniform base + lane*16
__device__ __forceinline__ void gll16(const void* gsrc, void* ldst) {
  __builtin_amdgcn_global_load_lds(
      (__attribute__((address_space(1))) unsigned int*)gsrc,
      (__attribute__((address_space(3))) unsigned int*)ldst, 16, 0, 0);
}

// ---------------- fused cast kernel: x (6144 blocks) + wq/wk/wv (576 each) ----------------
#define XN4 (SEQ * DIM / 4)     // 1572864
#define WN4 (DIM * DIM / 4)     // 147456

__global__ void cast_all_kernel(const float* __restrict__ x, const float* __restrict__ wq,
                                const float* __restrict__ wk, const float* __restrict__ wv,
                                unsigned short* __restrict__ dx, unsigned short* __restrict__ dq,
                                unsigned short* __restrict__ dk, unsigned short* __restrict__ dv) {
  int i = blockIdx.x * blockDim.x + threadIdx.x;
  const float* s;
  unsigned short* d;
  int off;
  if (i < XN4) {
    s = x; d = dx; off = i;
  } else {
    int j = i - XN4;
    int wi = j / WN4;
    off = j - wi * WN4;
    s = (wi == 0) ? wq : ((wi == 1) ? wk : wv);
    d = (wi == 0) ? dq : ((wi == 1) ? dk : dv);
  }
  float4 v = ((const float4*)s)[off];
  ushort4 r; r.x = f2bf(v.x); r.y = f2bf(v.y); r.z = f2bf(v.z); r.w = f2bf(v.w);
  ((ushort4*)d)[off] = r;
}

// ---------------- projection GEMM: C[m][n] = sum_k X[m][k]*W[n][k] ----------------
// z==0 writes Q fragment-linear: Qf[row>>4][col>>3][row&15][col&7]  (16B frag rows)
// z==1 writes K normal [row][dim]; z==2 writes Vt blocked [key>>5][vr][key&31]
__global__ __launch_bounds__(256, 2)
void proj_kernel(const unsigned short* __restrict__ X,
                 const unsigned short* __restrict__ Wq,
                 const unsigned short* __restrict__ Wk,
                 const unsigned short* __restrict__ Wv,
                 unsigned short* __restrict__ Qb,
                 unsigned short* __restrict__ Kb,
                 unsigned short* __restrict__ Vtb) {
  __shared__ __align__(16) char lds[65536];
  const int tid = threadIdx.x;
  const int lane = tid & 63, wv = tid >> 6;
  const int l15 = lane & 15, l4 = lane >> 4;
  const int mt = blockIdx.x, nt = blockIdx.y, z = blockIdx.z;
  const unsigned short* W = (z == 0) ? Wq : ((z == 1) ? Wk : Wv);

  f32x4 acc[4][4];
#pragma unroll
  for (int i = 0; i < 4; ++i)
#pragma unroll
    for (int j = 0; j < 4; ++j) acc[i][j] = f32x4{0.f, 0.f, 0.f, 0.f};

  auto stage = [&](int kk) {
    char* At = lds + (kk & 1) * 32768;
    char* Bt = At + 16384;
    const int d0 = kk * 64;
#pragma unroll
    for (int i = 0; i < 4; ++i) {
      int s = i * 256 + tid;
      int row = s >> 3, c = (s & 7) ^ (row & 7);
      gll16(X + (long)(mt * 128 + row) * DIM + d0 + c * 8, At + i * 4096 + (wv << 10));
      gll16(W + (long)(nt * 128 + row) * DIM + d0 + c * 8, Bt + i * 4096 + (wv << 10));
    }
  };

  stage(0);
#pragma unroll 1
  for (int kk = 0; kk < 12; ++kk) {
    __syncthreads();
    if (kk + 1 < 12) stage(kk + 1);
    const char* At = lds + (kk & 1) * 32768;
    const char* Bt = At + 16384;
#pragma unroll
    for (int ks = 0; ks < 2; ++ks) {
      const int c = ks * 4 + l4;
      s16x8 a[4], b[4];
#pragma unroll
      for (int mi = 0; mi < 4; ++mi) {
        int row = (wv & 1) * 64 + mi * 16 + l15;
        a[mi] = *(const s16x8*)(At + row * 128 + ((c ^ (row & 7)) << 4));
      }
#pragma unroll
      for (int ni = 0; ni < 4; ++ni) {
        int row = (wv >> 1) * 64 + ni * 16 + l15;
        b[ni] = *(const s16x8*)(Bt + row * 128 + ((c ^ (row & 7)) << 4));
      }
#pragma unroll
      for (int mi = 0; mi < 4; ++mi)
#pragma unroll
        for (int ni = 0; ni < 4; ++ni)
          acc[mi][ni] = __builtin_amdgcn_mfma_f32_16x16x32_bf16(a[mi], b[ni], acc[mi][ni], 0, 0, 0);
    }
  }

#pragma unroll
  for (int mi = 0; mi < 4; ++mi)
#pragma unroll
    for (int ni = 0; ni < 4; ++ni) {
      int row0 = mt * 128 + (wv & 1) * 64 + mi * 16 + l4 * 4;
      int col = nt * 128 + (wv >> 1) * 64 + ni * 16 + l15;
      if (z == 2) {
        ushort4 r;
        r.x = f2bf(acc[mi][ni][0]); r.y = f2bf(acc[mi][ni][1]);
        r.z = f2bf(acc[mi][ni][2]); r.w = f2bf(acc[mi][ni][3]);
        // blocked: [row0>>5][col][row0&31]; keys row0..row0+3 stay in one 32-block
        *(ushort4*)(Vtb + (long)(row0 >> 5) * (DIM * 32) + col * 32 + (row0 & 31)) = r;
      } else if (z == 0) {
        // fragment-linear Qf: [(row>>4)*96 + col>>3][row&15][col&7]
        const long fb = ((long)(row0 >> 4) * 96 + (col >> 3)) * 128 + (col & 7);
#pragma unroll
        for (int g = 0; g < 4; ++g)
          Qb[fb + (l4 * 4 + g) * 8] = f2bf(acc[mi][ni][g]);
      } else {
#pragma unroll
        for (int g = 0; g < 4; ++g)
          Kb[(long)(row0 + g) * DIM + col] = f2bf(acc[mi][ni][g]);
      }
    }
}

// ---------------- flash attention: R10 structure + Q-direct, af ISSUED BEFORE staging ----
// BM=64 q rows/block, BN=256 keys/iter, 8 waves, all 16x16x32 MFMA.
// vs R12 (332us, vmcnt-serialized): af global loads issue FIRST in each round
// (oldest vmem), so the MFMA's af-wait is vmcnt(5) and the 5 stageK loads stay
// in flight across the round — restores R10's one-round prefetch cover while
// keeping Q-direct (-27% LDS port reads, -96KB/iter staging writes).
// sched_barrier(0) pins af-before-stage issue order.
// K staging, 13 barriers/iter, rotation, PV (V direct ping-pong), P path,
// epilogue: byte-identical to R10/R12.
// LDS (98304): K B0=[0,32768) B1=[32768,65536); P=[65536,98304);
//   l_part aliases lds[0,1024) post-loop.
#define SCALE_LOG2E 0.05205878f  // (1/sqrt(768)) * log2(e)

#define LOADVB(arr, vv)                                                            \
  do {                                                                             \
    const unsigned short* Vb_ = V + (long)(kblk0 + (vv)) * (DIM * 32);             \
    _Pragma("unroll")                                                              \
    for (int j_ = 0; j_ < 6; ++j_)                                                 \
      arr[j_] = *(const s16x8*)(Vb_ + (j_ * 128 + wv * 16 + l15) * 32 + l4 * 8);   \
  } while (0)

#define PVCHUNK(vv, CUR, NXT)                                                      \
  do {                                                                             \
    if ((vv) + 1 < 8) LOADVB(NXT, (vv) + 1);                                       \
    s16x8 pa_[4];                                                                  \
    const int ck_ = (vv) * 4 + l4;                                                 \
    _Pragma("unroll")                                                              \
    for (int rs_ = 0; rs_ < 4; ++rs_) {                                            \
      int row_ = rs_ * 16 + l15;                                                   \
      int pc_ = (ck_ & ~7) | ((ck_ & 7) ^ (row_ & 7));                             \
      pa_[rs_] = *(const s16x8*)(Pl + row_ * 512 + (pc_ << 4));                    \
    }                                                                              \
    __builtin_amdgcn_s_setprio(1);                                                 \
    _Pragma("unroll")                                                              \
    for (int j_ = 0; j_ < 6; ++j_)                                                 \
      _Pragma("unroll")                                                            \
      for (int rs_ = 0; rs_ < 4; ++rs_)                                            \
        acc_o[rs_][j_] =                                                           \
            __builtin_amdgcn_mfma_f32_16x16x32_bf16(pa_[rs_], CUR[j_], acc_o[rs_][j_], 0, 0, 0); \
    __builtin_amdgcn_s_setprio(0);                                                 \
  } while (0)

__global__ __launch_bounds__(512, 2)
void flash_kernel(const unsigned short* __restrict__ Qf,  // fragment-linear Q
                  const unsigned short* __restrict__ K,   // [8192][768] bf16
                  const unsigned short* __restrict__ V,   // blocked Vt [256][768][32] bf16
                  unsigned short* __restrict__ partp,     // [G][8192][768] bf16 (G-split mode)
                  float* __restrict__ outf,               // [8192][768] fp32 (norm mode)
                  float* __restrict__ lout,               // [G][8192] (G-split mode)
                  int kv_len, int norm_out) {
  __shared__ __align__(16) char lds[98304];
  char* Pl = lds + 65536;
  float* l_part = (float*)lds;  // [4][64], used only after the main loop

  const int tid = threadIdx.x;
  const int lane = tid & 63, wv = tid >> 6;
  const int l15 = lane & 15, l4 = lane >> 4;
  const int qtile = blockIdx.x, split = blockIdx.y;
  const long kv0 = (long)split * kv_len;
  const long qrow0 = (long)qtile * 64;
  const int R = wv & 1;   // S row-half
  const int C = wv >> 1;  // S key-quarter

  f32x4 acc_o[4][6];
  float acc_lp[8];
#pragma unroll
  for (int i = 0; i < 4; ++i)
#pragma unroll
    for (int j = 0; j < 6; ++j) acc_o[i][j] = f32x4{0.f, 0.f, 0.f, 0.f};
#pragma unroll
  for (int i = 0; i < 8; ++i) acc_lp[i] = 0.f;

  const int niter = kv_len >> 8;

  // K stage: round r covers dims [r*64, r*64+64). 32KB, 128B rows, XOR-(row&7).
  auto stageK = [&](int r, long kbase) {
    char* Kc = lds + (r & 1) * 32768;
    const int d0 = r * 64;
#pragma unroll
    for (int i = 0; i < 4; ++i) {
      int s = i * 512 + tid;
      int row = s >> 3, c = (s & 7) ^ (row & 7);
      gll16(K + (kbase + row) * DIM + d0 + c * 8, Kc + i * 8192 + (wv << 10));
    }
  };

  stageK(0, kv0);
#pragma unroll 1
  for (int it = 0; it < niter; ++it) {
    const long kb = kv0 + (long)it * 256;
    const long kblk0 = kb >> 5;

    // ---- QK: S[64x256], per-wave region [32 rows x 64 keys] = 2x4 16x16 tiles ----
    f32x4 acc_s[2][4];
#pragma unroll
    for (int a = 0; a < 2; ++a)
#pragma unroll
      for (int b = 0; b < 4; ++b) acc_s[a][b] = f32x4{0.f, 0.f, 0.f, 0.f};

    const int tile16q = qtile * 4 + R * 2;   // +rt

#pragma unroll 1
    for (int r = 0; r < 12; ++r) {
      __syncthreads();  // drains stage(r); all waves done with prior compute
      // af FIRST (oldest vmem this round): MFMA's af-wait leaves staging in flight
      s16x8 af[2][2];
#pragma unroll
      for (int rt = 0; rt < 2; ++rt)
#pragma unroll
        for (int ks = 0; ks < 2; ++ks)
          af[rt][ks] = *(const s16x8*)(Qf +
              ((long)(tile16q + rt) * 96 + (r * 8 + ks * 4 + l4)) * 128 + l15 * 8);
      __builtin_amdgcn_sched_barrier(0);  // pin: staging must not hoist above af
      if (r + 1 < 12) stageK(r + 1, kb);
      else if (it + 1 < niter) stageK(0, kb + 256);  // dest B0; r=11 reads B1
      const char* Kc = lds + (r & 1) * 32768;
#pragma unroll
      for (int ks = 0; ks < 2; ++ks) {
        const int c = ks * 4 + l4;
        s16x8 bk[4];
#pragma unroll
        for (int ct = 0; ct < 4; ++ct) {
          int kr = C * 64 + ct * 16 + l15;
          bk[ct] = *(const s16x8*)(Kc + kr * 128 + ((c ^ (kr & 7)) << 4));
        }
        __builtin_amdgcn_s_setprio(1);
#pragma unroll
        for (int rt = 0; rt < 2; ++rt)
#pragma unroll
          for (int ct = 0; ct < 4; ++ct)
            acc_s[rt][ct] = __builtin_amdgcn_mfma_f32_16x16x32_bf16(af[rt][ks], bk[ct], acc_s[rt][ct], 0, 0, 0);
        __builtin_amdgcn_s_setprio(0);
      }
    }

    // ---- prefetch PV chunk 0's V fragments (latency hidden under exp phase) ----
    s16x8 vbA[6], vbB[6];
    LOADVB(vbA, 0);

    // ---- P = exp(S/sqrt(D)) -> bf16 -> LDS (swizzled [64][256]); per-lane l partials ----
#pragma unroll
    for (int rt = 0; rt < 2; ++rt)
#pragma unroll
      for (int ct = 0; ct < 4; ++ct)
#pragma unroll
        for (int g = 0; g < 4; ++g) {
          float p = exp2f(acc_s[rt][ct][g] * SCALE_LOG2E);
          acc_lp[rt * 4 + g] += p;
          int row = R * 32 + rt * 16 + l4 * 4 + g;
          int col = C * 64 + ct * 16 + l15;
          int off = row * 512 + ((((col >> 3) ^ (row & 7))) << 4) + ((col & 7) << 1);
          *(unsigned short*)(Pl + off) = f2bf(p);
        }
    __syncthreads();  // P visible to all waves (also drains vbA / next-iter K loads)

    // ---- PV: O[64x768] += P[64x256] @ V; 8 chunks; vb ping-pong from global ----
    PVCHUNK(0, vbA, vbB);
    PVCHUNK(1, vbB, vbA);
    PVCHUNK(2, vbA, vbB);
    PVCHUNK(3, vbB, vbA);
    PVCHUNK(4, vbA, vbB);
    PVCHUNK(5, vbB, vbA);
    PVCHUNK(6, vbA, vbB);
    PVCHUNK(7, vbB, vbA);
  }

  // ---- l reduction: butterfly over lane bits 0..3 (16 cols/group), combine quarters ----
#pragma unroll
  for (int i = 0; i < 8; ++i) {
    float v = acc_lp[i];
    v += __shfl_xor(v, 1); v += __shfl_xor(v, 2);
    v += __shfl_xor(v, 4); v += __shfl_xor(v, 8);
    acc_lp[i] = v;
  }
  __syncthreads();  // all staging/reads done before l_part alias use
  if (l15 == 0) {
#pragma unroll
    for (int rt = 0; rt < 2; ++rt)
#pragma unroll
      for (int g = 0; g < 4; ++g)
        l_part[C * 64 + R * 32 + rt * 16 + l4 * 4 + g] = acc_lp[rt * 4 + g];
  }
  __syncthreads();

  if (!norm_out) {
    if (tid < 64)
      lout[(long)split * SEQ + qrow0 + tid] =
          l_part[tid] + l_part[64 + tid] + l_part[128 + tid] + l_part[192 + tid];
#pragma unroll
    for (int rt = 0; rt < 4; ++rt) {
      int row = rt * 16 + l4 * 4;
#pragma unroll
      for (int j = 0; j < 6; ++j) {
        int cc = j >> 1, t = j & 1;
        int col = (cc * 16 + wv + 8 * t) * 16 + l15;
#pragma unroll
        for (int g = 0; g < 4; ++g)
          partp[(long)split * SEQ * DIM + (qrow0 + row + g) * DIM + col] = f2bf(acc_o[rt][j][g]);
      }
    }
  } else {
    float linv[4][4];
#pragma unroll
    for (int rt = 0; rt < 4; ++rt)
#pragma unroll
      for (int g = 0; g < 4; ++g) {
        int row = rt * 16 + l4 * 4 + g;
        linv[rt][g] = 1.0f / (l_part[row] + l_part[64 + row] + l_part[128 + row] + l_part[192 + row]);
      }
#pragma unroll
    for (int rt = 0; rt < 4; ++rt) {
      int row = rt * 16 + l4 * 4;
#pragma unroll
      for (int j = 0; j < 6; ++j) {
        int cc = j >> 1, t = j & 1;
        int col = (cc * 16 + wv + 8 * t) * 16 + l15;
#pragma unroll
        for (int g = 0; g < 4; ++g)
          outf[(qrow0 + row + g) * DIM + col] = acc_o[rt][j][g] * linv[rt][g];
      }
    }
  }
}

// ---------------- combine (G=2): out = (p0+p1)/(l0+l1), partials bf16 ----------------
__global__ void combine_kernel(const unsigned short* __restrict__ part,
                               const float* __restrict__ lsum,
                               float* __restrict__ out, int n4) {
  int i = blockIdx.x * blockDim.x + threadIdx.x;
  if (i >= n4) return;
  int row = (i * 4) / DIM;
  ushort4 p0 = ((const ushort4*)part)[i];
  ushort4 p1 = ((const ushort4*)(part + (long)SEQ * DIM))[i];
  float inv = 1.0f / (lsum[row] + lsum[SEQ + row]);
  float4 o;
  o.x = (bf2f(p0.x) + bf2f(p1.x)) * inv;
  o.y = (bf2f(p0.y) + bf2f(p1.y)) * inv;
  o.z = (bf2f(p0.z) + bf2f(p1.z)) * inv;
  o.w = (bf2f(p0.w) + bf2f(p1.w)) * inv;
  ((float4*)out)[i] = o;
}

// ---------------- host (G=2 max — the verified fast config) ----------------
extern "C" void kernel_launch(void* const* d_in, const int* in_sizes, int n_in,
                              void* d_out, int out_size, void* d_ws, size_t ws_size,
                              hipStream_t stream) {
  const float* x = (const float*)d_in[0];
  const float* wq = (const float*)d_in[1];
  const float* wk = (const float*)d_in[2];
  const float* wv = (const float*)d_in[3];
  float* out = (float*)d_out;
  char* ws = (char*)d_ws;

  const size_t o_xbf = 0;
  const size_t o_wq = o_xbf + (size_t)SEQ * DIM * 2;
  const size_t o_wk = o_wq + (size_t)DIM * DIM * 2;
  const size_t o_wv = o_wk + (size_t)DIM * DIM * 2;
  const size_t o_q = o_wv + (size_t)DIM * DIM * 2;
  const size_t o_k = o_q + (size_t)SEQ * DIM * 2;
  const size_t o_vt = o_k + (size_t)SEQ * DIM * 2;
  const size_t o_part = o_vt + (size_t)SEQ * DIM * 2;
  const size_t o_l = o_part + (size_t)2 * SEQ * DIM * 2;   // bf16 partials
  const size_t total_g2 = o_l + (size_t)2 * SEQ * 4;

  unsigned short* Xbf = (unsigned short*)(ws + o_xbf);
  unsigned short* Wqb = (unsigned short*)(ws + o_wq);
  unsigned short* Wkb = (unsigned short*)(ws + o_wk);
  unsigned short* Wvb = (unsigned short*)(ws + o_wv);
  unsigned short* Qb = (unsigned short*)(ws + o_q);   // fragment-linear Qf
  unsigned short* Kb = (unsigned short*)(ws + o_k);
  unsigned short* Vtb = (unsigned short*)(ws + o_vt);
  unsigned short* part = (unsigned short*)(ws + o_part);
  float* lbuf = (float*)(ws + o_l);

  const int G = (ws_size >= total_g2) ? 2 : 1;

  cast_all_kernel<<<7872, 256, 0, stream>>>(x, wq, wk, wv, Xbf, Wqb, Wkb, Wvb);
  proj_kernel<<<dim3(64, 6, 3), 256, 0, stream>>>(Xbf, Wqb, Wkb, Wvb, Qb, Kb, Vtb);
  if (G == 2) {
    flash_kernel<<<dim3(128, 2), 512, 0, stream>>>(Qb, Kb, Vtb, part, nullptr, lbuf, SEQ / 2, 0);
    combine_kernel<<<6144, 256, 0, stream>>>(part, lbuf, out, SEQ * DIM / 4);
  } else {
    flash_kernel<<<dim3(128, 1), 512, 0, stream>>>(Qb, Kb, Vtb, nullptr, out, nullptr, SEQ, 1);
  }
}

// Round 14
// 301.586 us; speedup vs baseline: 1.5260x; 1.1632x over previous
//
#include <hip/hip_runtime.h>

#define SEQ 8192
#define DIM 768

typedef __attribute__((ext_vector_type(8))) short s16x8;   // 8 x bf16
typedef __attribute__((ext_vector_type(4))) float f32x4;

// RNE float -> bf16
__device__ __forceinline__ unsigned short f2bf(float f) {
  union { float f; unsigned u; } v; v.f = f;
  unsigned r = v.u + 0x7FFFu + ((v.u >> 16) & 1u);
  return (unsigned short)(r >> 16);
}

__device__ __forceinline__ float bf2f(unsigned short s) {
  union { unsigned u; float f; } v; v.u = ((unsigned)s) << 16;
  return v.f;
}

// async global->LDS 16B copy: lds dest = wave-uniform base + lane*16
__device__ __forceinline__ void gll16(const void* gsrc, void* ldst) {
  __builtin_amdgcn_global_load_lds(
      (__attribute__((address_space(1))) unsigned int*)gsrc,
      (__attribute__((address_space(3))) unsigned int*)ldst, 16, 0, 0);
}

// ---------------- fused cast kernel: x (6144 blocks) + wq/wk/wv (576 each) ----------------
#define XN4 (SEQ * DIM / 4)     // 1572864
#define WN4 (DIM * DIM / 4)     // 147456

__global__ void cast_all_kernel(const float* __restrict__ x, const float* __restrict__ wq,
                                const float* __restrict__ wk, const float* __restrict__ wv,
                                unsigned short* __restrict__ dx, unsigned short* __restrict__ dq,
                                unsigned short* __restrict__ dk, unsigned short* __restrict__ dv) {
  int i = blockIdx.x * blockDim.x + threadIdx.x;
  const float* s;
  unsigned short* d;
  int off;
  if (i < XN4) {
    s = x; d = dx; off = i;
  } else {
    int j = i - XN4;
    int wi = j / WN4;
    off = j - wi * WN4;
    s = (wi == 0) ? wq : ((wi == 1) ? wk : wv);
    d = (wi == 0) ? dq : ((wi == 1) ? dk : dv);
  }
  float4 v = ((const float4*)s)[off];
  ushort4 r; r.x = f2bf(v.x); r.y = f2bf(v.y); r.z = f2bf(v.z); r.w = f2bf(v.w);
  ((ushort4*)d)[off] = r;
}

// ---------------- projection GEMM: C[m][n] = sum_k X[m][k]*W[n][k] ----------------
// z==2 writes V in key-blocked layout: Vt_blk[key>>5][vr 768][key&31]
__global__ __launch_bounds__(256, 2)
void proj_kernel(const unsigned short* __restrict__ X,
                 const unsigned short* __restrict__ Wq,
                 const unsigned short* __restrict__ Wk,
                 const unsigned short* __restrict__ Wv,
                 unsigned short* __restrict__ Qb,
                 unsigned short* __restrict__ Kb,
                 unsigned short* __restrict__ Vtb) {
  __shared__ __align__(16) char lds[65536];
  const int tid = threadIdx.x;
  const int lane = tid & 63, wv = tid >> 6;
  const int l15 = lane & 15, l4 = lane >> 4;
  const int mt = blockIdx.x, nt = blockIdx.y, z = blockIdx.z;
  const unsigned short* W = (z == 0) ? Wq : ((z == 1) ? Wk : Wv);

  f32x4 acc[4][4];
#pragma unroll
  for (int i = 0; i < 4; ++i)
#pragma unroll
    for (int j = 0; j < 4; ++j) acc[i][j] = f32x4{0.f, 0.f, 0.f, 0.f};

  auto stage = [&](int kk) {
    char* At = lds + (kk & 1) * 32768;
    char* Bt = At + 16384;
    const int d0 = kk * 64;
#pragma unroll
    for (int i = 0; i < 4; ++i) {
      int s = i * 256 + tid;
      int row = s >> 3, c = (s & 7) ^ (row & 7);
      gll16(X + (long)(mt * 128 + row) * DIM + d0 + c * 8, At + i * 4096 + (wv << 10));
      gll16(W + (long)(nt * 128 + row) * DIM + d0 + c * 8, Bt + i * 4096 + (wv << 10));
    }
  };

  stage(0);
#pragma unroll 1
  for (int kk = 0; kk < 12; ++kk) {
    __syncthreads();
    if (kk + 1 < 12) stage(kk + 1);
    const char* At = lds + (kk & 1) * 32768;
    const char* Bt = At + 16384;
#pragma unroll
    for (int ks = 0; ks < 2; ++ks) {
      const int c = ks * 4 + l4;
      s16x8 a[4], b[4];
#pragma unroll
      for (int mi = 0; mi < 4; ++mi) {
        int row = (wv & 1) * 64 + mi * 16 + l15;
        a[mi] = *(const s16x8*)(At + row * 128 + ((c ^ (row & 7)) << 4));
      }
#pragma unroll
      for (int ni = 0; ni < 4; ++ni) {
        int row = (wv >> 1) * 64 + ni * 16 + l15;
        b[ni] = *(const s16x8*)(Bt + row * 128 + ((c ^ (row & 7)) << 4));
      }
#pragma unroll
      for (int mi = 0; mi < 4; ++mi)
#pragma unroll
        for (int ni = 0; ni < 4; ++ni)
          acc[mi][ni] = __builtin_amdgcn_mfma_f32_16x16x32_bf16(a[mi], b[ni], acc[mi][ni], 0, 0, 0);
    }
  }

#pragma unroll
  for (int mi = 0; mi < 4; ++mi)
#pragma unroll
    for (int ni = 0; ni < 4; ++ni) {
      int row0 = mt * 128 + (wv & 1) * 64 + mi * 16 + l4 * 4;
      int col = nt * 128 + (wv >> 1) * 64 + ni * 16 + l15;
      if (z == 2) {
        ushort4 r;
        r.x = f2bf(acc[mi][ni][0]); r.y = f2bf(acc[mi][ni][1]);
        r.z = f2bf(acc[mi][ni][2]); r.w = f2bf(acc[mi][ni][3]);
        // blocked: [row0>>5][col][row0&31]; keys row0..row0+3 stay in one 32-block
        *(ushort4*)(Vtb + (long)(row0 >> 5) * (DIM * 32) + col * 32 + (row0 & 31)) = r;
      } else {
        unsigned short* dst = (z == 0) ? Qb : Kb;
#pragma unroll
        for (int g = 0; g < 4; ++g)
          dst[(long)(row0 + g) * DIM + col] = f2bf(acc[mi][ni][g]);
      }
    }
}

// ---------------- flash attention: QK = R4/R9 verbatim; PV = V direct global->reg ----
// BM=64 q rows/block, BN=256 keys/iter, 8 waves, all 16x16x32 MFMA.
// V is NOT staged in LDS: blocked-Vt fragment reads are already coalesced
// (16 lanes x 64B stride, l4 fills each 64B line -> 16 full lines/wave-load).
// vb ping-pong: chunk v's MFMAs run while chunk v+1's 6 loads are in flight.
// LDS (114688): QK B0=[0,40960) B1=[40960,81920); P=[81920,114688);
//   l_part aliases lds[0,1024) post-loop. Barriers: 12 QK + 1 P-visibility = 13/iter.
// Rotation: QK r reads buf r&1, stages buf (r+1)&1; r=11 (reads B1) stages
//   next-iter QK(0) -> B0 (B0 last read r=10, all waves past r=11 barrier).
// P hazard: P read in PV (barrier-free); next P write is after 12 next-iter QK
//   barriers -> every wave has finished PV before any wave rewrites P.
#define SCALE_LOG2E 0.05205878f  // (1/sqrt(768)) * log2(e)

#define LOADVB(arr, vv)                                                            \
  do {                                                                             \
    const unsigned short* Vb_ = V + (long)(kblk0 + (vv)) * (DIM * 32);             \
    _Pragma("unroll")                                                              \
    for (int j_ = 0; j_ < 6; ++j_)                                                 \
      arr[j_] = *(const s16x8*)(Vb_ + (j_ * 128 + wv * 16 + l15) * 32 + l4 * 8);   \
  } while (0)

#define PVCHUNK(vv, CUR, NXT)                                                      \
  do {                                                                             \
    if ((vv) + 1 < 8) LOADVB(NXT, (vv) + 1);                                       \
    s16x8 pa_[4];                                                                  \
    const int ck_ = (vv) * 4 + l4;                                                 \
    _Pragma("unroll")                                                              \
    for (int rs_ = 0; rs_ < 4; ++rs_) {                                            \
      int row_ = rs_ * 16 + l15;                                                   \
      int pc_ = (ck_ & ~7) | ((ck_ & 7) ^ (row_ & 7));                             \
      pa_[rs_] = *(const s16x8*)(Pl + row_ * 512 + (pc_ << 4));                    \
    }                                                                              \
    __builtin_amdgcn_s_setprio(1);                                                 \
    _Pragma("unroll")                                                              \
    for (int j_ = 0; j_ < 6; ++j_)                                                 \
      _Pragma("unroll")                                                            \
      for (int rs_ = 0; rs_ < 4; ++rs_)                                            \
        acc_o[rs_][j_] =                                                           \
            __builtin_amdgcn_mfma_f32_16x16x32_bf16(pa_[rs_], CUR[j_], acc_o[rs_][j_], 0, 0, 0); \
    __builtin_amdgcn_s_setprio(0);                                                 \
  } while (0)

__global__ __launch_bounds__(512, 2)
void flash_kernel(const unsigned short* __restrict__ Q,   // [8192][768] bf16
                  const unsigned short* __restrict__ K,   // [8192][768] bf16
                  const unsigned short* __restrict__ V,   // blocked Vt [256][768][32] bf16
                  unsigned short* __restrict__ partp,     // [G][8192][768] bf16 (G-split mode)
                  float* __restrict__ outf,               // [8192][768] fp32 (norm mode)
                  float* __restrict__ lout,               // [G][8192] (G-split mode)
                  int kv_len, int norm_out) {
  __shared__ __align__(16) char lds[114688];
  char* Pl = lds + 81920;
  float* l_part = (float*)lds;  // [4][64], used only after the main loop

  const int tid = threadIdx.x;
  const int lane = tid & 63, wv = tid >> 6;
  const int l15 = lane & 15, l4 = lane >> 4;
  const int qtile = blockIdx.x, split = blockIdx.y;
  const long kv0 = (long)split * kv_len;
  const long qrow0 = (long)qtile * 64;
  const int R = wv & 1;   // S row-half
  const int C = wv >> 1;  // S key-quarter

  f32x4 acc_o[4][6];
  float acc_lp[8];
#pragma unroll
  for (int i = 0; i < 4; ++i)
#pragma unroll
    for (int j = 0; j < 6; ++j) acc_o[i][j] = f32x4{0.f, 0.f, 0.f, 0.f};
#pragma unroll
  for (int i = 0; i < 8; ++i) acc_lp[i] = 0.f;

  const int niter = kv_len >> 8;

  auto stageQK = [&](int r, long kbase) {
    char* Qc = lds + (r & 1) * 40960;
    char* Kc = Qc + 8192;
    const int d0 = r * 64;
    {
      int s = tid;
      int row = s >> 3, c = (s & 7) ^ (row & 7);
      gll16(Q + (qrow0 + row) * DIM + d0 + c * 8, Qc + (wv << 10));
    }
#pragma unroll
    for (int i = 0; i < 4; ++i) {
      int s = i * 512 + tid;
      int row = s >> 3, c = (s & 7) ^ (row & 7);
      gll16(K + (kbase + row) * DIM + d0 + c * 8, Kc + i * 8192 + (wv << 10));
    }
  };

  stageQK(0, kv0);
#pragma unroll 1
  for (int it = 0; it < niter; ++it) {
    const long kb = kv0 + (long)it * 256;
    const long kblk0 = kb >> 5;

    // ---- QK: S[64x256], per-wave region [32 rows x 64 keys] = 2x4 16x16 tiles ----
    f32x4 acc_s[2][4];
#pragma unroll
    for (int a = 0; a < 2; ++a)
#pragma unroll
      for (int b = 0; b < 4; ++b) acc_s[a][b] = f32x4{0.f, 0.f, 0.f, 0.f};

#pragma unroll 1
    for (int r = 0; r < 12; ++r) {
      __syncthreads();  // drains stage(r); all waves done with prior compute
      if (r + 1 < 12) stageQK(r + 1, kb);
      else if (it + 1 < niter) stageQK(0, kb + 256);  // dest B0; r=11 reads B1
      const char* Qc = lds + (r & 1) * 40960;
      const char* Kc = Qc + 8192;
#pragma unroll
      for (int ks = 0; ks < 2; ++ks) {
        const int c = ks * 4 + l4;
        s16x8 af[2], bk[4];
#pragma unroll
        for (int rt = 0; rt < 2; ++rt) {
          int row = R * 32 + rt * 16 + l15;
          af[rt] = *(const s16x8*)(Qc + row * 128 + ((c ^ (row & 7)) << 4));
        }
#pragma unroll
        for (int ct = 0; ct < 4; ++ct) {
          int kr = C * 64 + ct * 16 + l15;
          bk[ct] = *(const s16x8*)(Kc + kr * 128 + ((c ^ (kr & 7)) << 4));
        }
        __builtin_amdgcn_s_setprio(1);
#pragma unroll
        for (int rt = 0; rt < 2; ++rt)
#pragma unroll
          for (int ct = 0; ct < 4; ++ct)
            acc_s[rt][ct] = __builtin_amdgcn_mfma_f32_16x16x32_bf16(af[rt], bk[ct], acc_s[rt][ct], 0, 0, 0);
        __builtin_amdgcn_s_setprio(0);
      }
    }

    // ---- prefetch PV chunk 0's V fragments (latency hidden under exp phase) ----
    s16x8 vbA[6], vbB[6];
    LOADVB(vbA, 0);

    // ---- P = exp(S/sqrt(D)) -> bf16 -> LDS (swizzled [64][256]); per-lane l partials ----
#pragma unroll
    for (int rt = 0; rt < 2; ++rt)
#pragma unroll
      for (int ct = 0; ct < 4; ++ct)
#pragma unroll
        for (int g = 0; g < 4; ++g) {
          float p = exp2f(acc_s[rt][ct][g] * SCALE_LOG2E);
          acc_lp[rt * 4 + g] += p;
          int row = R * 32 + rt * 16 + l4 * 4 + g;
          int col = C * 64 + ct * 16 + l15;
          int off = row * 512 + ((((col >> 3) ^ (row & 7))) << 4) + ((col & 7) << 1);
          *(unsigned short*)(Pl + off) = f2bf(p);
        }
    __syncthreads();  // P visible to all waves (also drains vbA / QK0' loads)

    // ---- PV: O[64x768] += P[64x256] @ V; 8 chunks; vb ping-pong from global ----
    PVCHUNK(0, vbA, vbB);
    PVCHUNK(1, vbB, vbA);
    PVCHUNK(2, vbA, vbB);
    PVCHUNK(3, vbB, vbA);
    PVCHUNK(4, vbA, vbB);
    PVCHUNK(5, vbB, vbA);
    PVCHUNK(6, vbA, vbB);
    PVCHUNK(7, vbB, vbA);
  }

  // ---- l reduction: butterfly over lane bits 0..3 (16 cols/group), combine quarters ----
#pragma unroll
  for (int i = 0; i < 8; ++i) {
    float v = acc_lp[i];
    v += __shfl_xor(v, 1); v += __shfl_xor(v, 2);
    v += __shfl_xor(v, 4); v += __shfl_xor(v, 8);
    acc_lp[i] = v;
  }
  __syncthreads();  // all staging/reads done before l_part alias use
  if (l15 == 0) {
#pragma unroll
    for (int rt = 0; rt < 2; ++rt)
#pragma unroll
      for (int g = 0; g < 4; ++g)
        l_part[C * 64 + R * 32 + rt * 16 + l4 * 4 + g] = acc_lp[rt * 4 + g];
  }
  __syncthreads();

  if (!norm_out) {
    if (tid < 64)
      lout[(long)split * SEQ + qrow0 + tid] =
          l_part[tid] + l_part[64 + tid] + l_part[128 + tid] + l_part[192 + tid];
#pragma unroll
    for (int rt = 0; rt < 4; ++rt) {
      int row = rt * 16 + l4 * 4;
#pragma unroll
      for (int j = 0; j < 6; ++j) {
        int cc = j >> 1, t = j & 1;
        int col = (cc * 16 + wv + 8 * t) * 16 + l15;
#pragma unroll
        for (int g = 0; g < 4; ++g)
          partp[(long)split * SEQ * DIM + (qrow0 + row + g) * DIM + col] = f2bf(acc_o[rt][j][g]);
      }
    }
  } else {
    float linv[4][4];
#pragma unroll
    for (int rt = 0; rt < 4; ++rt)
#pragma unroll
      for (int g = 0; g < 4; ++g) {
        int row = rt * 16 + l4 * 4 + g;
        linv[rt][g] = 1.0f / (l_part[row] + l_part[64 + row] + l_part[128 + row] + l_part[192 + row]);
      }
#pragma unroll
    for (int rt = 0; rt < 4; ++rt) {
      int row = rt * 16 + l4 * 4;
#pragma unroll
      for (int j = 0; j < 6; ++j) {
        int cc = j >> 1, t = j & 1;
        int col = (cc * 16 + wv + 8 * t) * 16 + l15;
#pragma unroll
        for (int g = 0; g < 4; ++g)
          outf[(qrow0 + row + g) * DIM + col] = acc_o[rt][j][g] * linv[rt][g];
      }
    }
  }
}

// ---------------- combine (G=2): out = (p0+p1)/(l0+l1), partials bf16 ----------------
__global__ void combine_kernel(const unsigned short* __restrict__ part,
                               const float* __restrict__ lsum,
                               float* __restrict__ out, int n4) {
  int i = blockIdx.x * blockDim.x + threadIdx.x;
  if (i >= n4) return;
  int row = (i * 4) / DIM;
  ushort4 p0 = ((const ushort4*)part)[i];
  ushort4 p1 = ((const ushort4*)(part + (long)SEQ * DIM))[i];
  float inv = 1.0f / (lsum[row] + lsum[SEQ + row]);
  float4 o;
  o.x = (bf2f(p0.x) + bf2f(p1.x)) * inv;
  o.y = (bf2f(p0.y) + bf2f(p1.y)) * inv;
  o.z = (bf2f(p0.z) + bf2f(p1.z)) * inv;
  o.w = (bf2f(p0.w) + bf2f(p1.w)) * inv;
  ((float4*)out)[i] = o;
}

// ---------------- host (G=2 max — the verified fast config) ----------------
extern "C" void kernel_launch(void* const* d_in, const int* in_sizes, int n_in,
                              void* d_out, int out_size, void* d_ws, size_t ws_size,
                              hipStream_t stream) {
  const float* x = (const float*)d_in[0];
  const float* wq = (const float*)d_in[1];
  const float* wk = (const float*)d_in[2];
  const float* wv = (const float*)d_in[3];
  float* out = (float*)d_out;
  char* ws = (char*)d_ws;

  const size_t o_xbf = 0;
  const size_t o_wq = o_xbf + (size_t)SEQ * DIM * 2;
  const size_t o_wk = o_wq + (size_t)DIM * DIM * 2;
  const size_t o_wv = o_wk + (size_t)DIM * DIM * 2;
  const size_t o_q = o_wv + (size_t)DIM * DIM * 2;
  const size_t o_k = o_q + (size_t)SEQ * DIM * 2;
  const size_t o_vt = o_k + (size_t)SEQ * DIM * 2;
  const size_t o_part = o_vt + (size_t)SEQ * DIM * 2;
  const size_t o_l = o_part + (size_t)2 * SEQ * DIM * 2;   // bf16 partials
  const size_t total_g2 = o_l + (size_t)2 * SEQ * 4;

  unsigned short* Xbf = (unsigned short*)(ws + o_xbf);
  unsigned short* Wqb = (unsigned short*)(ws + o_wq);
  unsigned short* Wkb = (unsigned short*)(ws + o_wk);
  unsigned short* Wvb = (unsigned short*)(ws + o_wv);
  unsigned short* Qb = (unsigned short*)(ws + o_q);
  unsigned short* Kb = (unsigned short*)(ws + o_k);
  unsigned short* Vtb = (unsigned short*)(ws + o_vt);
  unsigned short* part = (unsigned short*)(ws + o_part);
  float* lbuf = (float*)(ws + o_l);

  const int G = (ws_size >= total_g2) ? 2 : 1;

  cast_all_kernel<<<7872, 256, 0, stream>>>(x, wq, wk, wv, Xbf, Wqb, Wkb, Wvb);
  proj_kernel<<<dim3(64, 6, 3), 256, 0, stream>>>(Xbf, Wqb, Wkb, Wvb, Qb, Kb, Vtb);
  if (G == 2) {
    flash_kernel<<<dim3(128, 2), 512, 0, stream>>>(Qb, Kb, Vtb, part, nullptr, lbuf, SEQ / 2, 0);
    combine_kernel<<<6144, 256, 0, stream>>>(part, lbuf, out, SEQ * DIM / 4);
  } else {
    flash_kernel<<<dim3(128, 1), 512, 0, stream>>>(Qb, Kb, Vtb, nullptr, out, nullptr, SEQ, 1);
  }
}